// Round 6
// baseline (1571.485 us; speedup 1.0000x reference)
//
#include <hip/hip_runtime.h>
#include <hip/hip_bf16.h>

#define ALPHA_F 0.1f
#define KSTEPS 10
#define BKT_SH 9                       // 512 dst rows per bucket
#define P1_CHUNK 8192

typedef __attribute__((ext_vector_type(8))) short bf16x8;
typedef __attribute__((ext_vector_type(4))) float f32x4;

__device__ __forceinline__ unsigned short f2bf(float f) {
  union { float f; unsigned int u; } v; v.f = f;
  unsigned int u = v.u;
  u += 0x7FFFu + ((u >> 16) & 1u);   // round-to-nearest-even
  return (unsigned short)(u >> 16);
}
__device__ __forceinline__ float bflo(unsigned int u) { return __uint_as_float(u << 16); }
__device__ __forceinline__ float bfhi(unsigned int u) { return __uint_as_float(u & 0xFFFF0000u); }

__device__ __forceinline__ void gload16(const void* g, void* l) {
  __builtin_amdgcn_global_load_lds(
      (const __attribute__((address_space(1))) void*)g,
      (__attribute__((address_space(3))) void*)l, 16, 0, 0);
}

// ============ CSR build: two-level binned counting sort ============

__global__ __launch_bounds__(256)
void p0_hist(const int* __restrict__ dstv, int E, int* __restrict__ bhist) {
  __shared__ int h[256];
  int t = threadIdx.x;
  h[t] = 0;
  __syncthreads();
  int b0 = blockIdx.x * P1_CHUNK;
  int lim = min(P1_CHUNK, E - b0);
  for (int i = t; i < lim; i += 256) atomicAdd(&h[dstv[b0 + i] >> BKT_SH], 1);
  __syncthreads();
  if (h[t]) atomicAdd(&bhist[t], h[t]);
}

__global__ void p0_scan(const int* __restrict__ bhist, int* __restrict__ bbase,
                        int* __restrict__ gcur, int* __restrict__ rowptr, int N, int E) {
  __shared__ int s[256];
  int t = threadIdx.x;
  int mine = bhist[t];
  s[t] = mine;
  __syncthreads();
  for (int off = 1; off < 256; off <<= 1) {
    int v = (t >= off) ? s[t - off] : 0;
    __syncthreads();
    s[t] += v;
    __syncthreads();
  }
  int excl = s[t] - mine;
  bbase[t] = excl;
  gcur[t] = excl;
  if (t == 0) rowptr[N] = E;
}

__global__ __launch_bounds__(256)
void p1_scatter(const int* __restrict__ srcv, const int* __restrict__ dstv, int E,
                int* __restrict__ gcur, int2* __restrict__ tmp) {
  __shared__ int h[256];
  __shared__ int loc[256];
  int t = threadIdx.x;
  int b0 = blockIdx.x * P1_CHUNK;
  int lim = min(P1_CHUNK, E - b0);
  h[t] = 0;
  __syncthreads();
  for (int i = t; i < lim; i += 256) atomicAdd(&h[dstv[b0 + i] >> BKT_SH], 1);
  __syncthreads();
  loc[t] = h[t] ? atomicAdd(&gcur[t], h[t]) : 0;
  __syncthreads();
  h[t] = 0;
  __syncthreads();
  for (int i = t; i < lim; i += 256) {
    int d = dstv[b0 + i], s = srcv[b0 + i];
    int b = d >> BKT_SH;
    int pos = loc[b] + atomicAdd(&h[b], 1);
    tmp[pos] = make_int2(s, d);
  }
}

// p2: one block per bucket — counts, rowptr, in-bucket sort; emits COLUMN ONLY (y-trick)
__global__ __launch_bounds__(256)
void p2_bucket(const int2* __restrict__ tmp, const int* __restrict__ bbase,
               const int* __restrict__ bhist, int* __restrict__ counts,
               int* __restrict__ rowptr, int* __restrict__ col, int N) {
  __shared__ int h1[512];
  __shared__ int cur[512];
  __shared__ int s2[256];
  const int t = threadIdx.x;
  const int b = blockIdx.x;
  const int base = bbase[b];
  const int sz = bhist[b];
  const int r0 = b << BKT_SH;
  const int nrows = min(512, N - r0);

  h1[t] = 0; h1[t + 256] = 0;
  __syncthreads();
  for (int i = t; i < sz; i += 256) atomicAdd(&h1[tmp[base + i].y - r0], 1);
  __syncthreads();
  if (t < nrows) counts[r0 + t] = h1[t];
  if (t + 256 < nrows) counts[r0 + t + 256] = h1[t + 256];
  int a = h1[2 * t], c = h1[2 * t + 1];
  s2[t] = a + c;
  __syncthreads();
  for (int off = 1; off < 256; off <<= 1) {
    int v = (t >= off) ? s2[t - off] : 0;
    __syncthreads();
    s2[t] += v;
    __syncthreads();
  }
  int excl2 = s2[t] - (a + c);
  cur[2 * t] = excl2;
  cur[2 * t + 1] = excl2 + a;
  __syncthreads();
  if (t < nrows) rowptr[r0 + t] = base + cur[t];
  if (t + 256 < nrows) rowptr[r0 + t + 256] = base + cur[t + 256];
  __syncthreads();
  for (int i = t; i < sz; i += 256) {
    int2 e = tmp[base + i];
    int p = base + atomicAdd(&cur[e.y - r0], 1);
    col[p] = e.x;
  }
}

__global__ void k_dis(const int* __restrict__ counts, float* __restrict__ dis, int N) {
  int i = blockIdx.x * 256 + threadIdx.x;
  if (i < N) dis[i] = rsqrtf((float)(counts[i] + 1));  // +1 self-loop
}

// zero the pad row (index N) of both y buffers (all 4 quarters)
__global__ void k_zrow(unsigned short* __restrict__ yA, unsigned short* __restrict__ yB, int N) {
  int t = threadIdx.x;                 // 128 threads
  size_t N1 = (size_t)N + 1;
  if (t < 64)      yA[((size_t)(t >> 4) * N1 + N) * 16 + (t & 15)] = 0;
  else { int u = t - 64; yB[((size_t)(u >> 4) * N1 + N) * 16 + (u & 15)] = 0; }
}

// ============ weight conversion to MFMA-native tiled layouts ============
// W1 [512][256] -> WT1t: [kstep8][nsub16][q8][n16][e8]
__global__ void k_wconv1(const float* __restrict__ W, unsigned short* __restrict__ WT) {
  int idx = blockIdx.x * 256 + threadIdx.x;
  if (idx >= 512 * 256) return;
  int e = idx & 7, n = (idx >> 3) & 15, q = (idx >> 7) & 7;
  int nsub = (idx >> 10) & 15, kstep = idx >> 14;
  int k = kstep * 64 + q * 8 + e;
  int ncol = nsub * 16 + n;
  WT[idx] = f2bf(W[(size_t)k * 256 + ncol]);
}

// W2 [256][64] -> WT2t: [kstep4][nsub4][q8][n16][e8]
__global__ void k_wconv2(const float* __restrict__ W, unsigned short* __restrict__ WT) {
  int idx = blockIdx.x * 256 + threadIdx.x;
  if (idx >= 256 * 64) return;
  int e = idx & 7, n = (idx >> 3) & 15, q = (idx >> 7) & 7;
  int nsub = (idx >> 10) & 3, kstep = idx >> 12;
  int k = kstep * 64 + q * 8 + e;
  int ncol = nsub * 16 + n;
  WT[idx] = f2bf(W[(size_t)k * 64 + ncol]);
}

// ============ GEMM1: hid_tiled = relu(x @ W1 + b1), BM=128 BN=256 BK=64 ============
__global__ __launch_bounds__(512)
void gemm1_kernel(const float* __restrict__ X, const unsigned short* __restrict__ Bt,
                  const float* __restrict__ bias, unsigned short* __restrict__ outT,
                  int M) {
  __shared__ __align__(16) unsigned short Al[8192];    // 16 KB
  __shared__ __align__(16) unsigned short Bl[16384];   // 32 KB
  const int t = threadIdx.x;
  const int m0 = blockIdx.x * 128;
  const int lane = t & 63;
  const int w = t >> 6;
  const int wm = w >> 2, wn = w & 3;

  const int sm = ((t >> 7) << 4) + (t & 15);
  const int sq = (t >> 4) & 7;
  const int r1 = m0 + sm;
  const int r2 = r1 + 64;
  const bool g1 = r1 < M, g2 = r2 < M;

  f32x4 acc[4][4] = {};

  for (int ks = 0; ks < 8; ++ks) {
    const int kc = ks * 64 + sq * 8;
    uint4 v1 = {0, 0, 0, 0}, v2 = {0, 0, 0, 0};
    if (g1) {
      const float* p = X + (size_t)r1 * 512 + kc;
      float4 a = *(const float4*)p, b = *(const float4*)(p + 4);
      unsigned short* o = (unsigned short*)&v1;
      o[0] = f2bf(a.x); o[1] = f2bf(a.y); o[2] = f2bf(a.z); o[3] = f2bf(a.w);
      o[4] = f2bf(b.x); o[5] = f2bf(b.y); o[6] = f2bf(b.z); o[7] = f2bf(b.w);
    }
    if (g2) {
      const float* p = X + (size_t)r2 * 512 + kc;
      float4 a = *(const float4*)p, b = *(const float4*)(p + 4);
      unsigned short* o = (unsigned short*)&v2;
      o[0] = f2bf(a.x); o[1] = f2bf(a.y); o[2] = f2bf(a.z); o[3] = f2bf(a.w);
      o[4] = f2bf(b.x); o[5] = f2bf(b.y); o[6] = f2bf(b.z); o[7] = f2bf(b.w);
    }
    *(uint4*)&Al[t * 8] = v1;
    *(uint4*)&Al[(t + 512) * 8] = v2;

    const unsigned short* bs = Bt + ks * 16384;
    gload16(bs + (size_t)t * 8,          &Bl[t * 8]);
    gload16(bs + (size_t)(t + 512) * 8,  &Bl[(t + 512) * 8]);
    gload16(bs + (size_t)(t + 1024) * 8, &Bl[(t + 1024) * 8]);
    gload16(bs + (size_t)(t + 1536) * 8, &Bl[(t + 1536) * 8]);
    __syncthreads();

#pragma unroll
    for (int kk = 0; kk < 2; ++kk) {
      bf16x8 af[4], bfv[4];
#pragma unroll
      for (int mi = 0; mi < 4; ++mi)
        af[mi] = *(const bf16x8*)&Al[((wm * 4 + mi) * 128 + kk * 64 + (lane >> 4) * 16 + (lane & 15)) * 8];
#pragma unroll
      for (int ni = 0; ni < 4; ++ni)
        bfv[ni] = *(const bf16x8*)&Bl[((wn * 4 + ni) * 128 + kk * 64 + (lane >> 4) * 16 + (lane & 15)) * 8];
#pragma unroll
      for (int mi = 0; mi < 4; ++mi)
#pragma unroll
        for (int ni = 0; ni < 4; ++ni)
          acc[mi][ni] = __builtin_amdgcn_mfma_f32_16x16x32_bf16(af[mi], bfv[ni], acc[mi][ni], 0, 0, 0);
    }
    __syncthreads();
  }

  unsigned short* ob = outT + (size_t)blockIdx.x * 32768;
#pragma unroll
  for (int mi = 0; mi < 4; ++mi) {
#pragma unroll
    for (int ni = 0; ni < 4; ++ni) {
      int n = wn * 64 + ni * 16 + (lane & 15);
      float bv = bias[n];
      int kstep = n >> 6, q = (n >> 3) & 7, e = n & 7;
#pragma unroll
      for (int j = 0; j < 4; ++j) {
        int lm = wm * 64 + mi * 16 + (lane >> 4) * 4 + j;
        if (m0 + lm < M) {
          float v = fmaxf(acc[mi][ni][j] + bv, 0.f);
          int msub = lm >> 4, mm = lm & 15;
          ob[((((kstep * 8 + msub) * 8 + q) * 16 + mm) * 8) + e] = f2bf(v);
        }
      }
    }
  }
}

// ============ GEMM2: quartered h and y0 = dis*h, BM=128 BN=64 BK=64 ============
__global__ __launch_bounds__(256)
void gemm2_kernel(const unsigned short* __restrict__ At, const unsigned short* __restrict__ Bt,
                  const float* __restrict__ bias, const float* __restrict__ dis,
                  unsigned short* __restrict__ hq, unsigned short* __restrict__ y0, int M) {
  __shared__ __align__(16) unsigned short Al[8192];
  __shared__ __align__(16) unsigned short Bl[4096];
  const int t = threadIdx.x;
  const int m0 = blockIdx.x * 128;
  const int lane = t & 63;
  const int w = t >> 6;
  const int wm = w >> 1, wn = w & 1;
  const size_t N1 = (size_t)M + 1;

  f32x4 acc[4][2] = {};

  const unsigned short* ab = At + (size_t)blockIdx.x * 32768;
  for (int ks = 0; ks < 4; ++ks) {
    const unsigned short* as = ab + ks * 8192;
    gload16(as + (size_t)t * 8,         &Al[t * 8]);
    gload16(as + (size_t)(t + 256) * 8, &Al[(t + 256) * 8]);
    gload16(as + (size_t)(t + 512) * 8, &Al[(t + 512) * 8]);
    gload16(as + (size_t)(t + 768) * 8, &Al[(t + 768) * 8]);
    const unsigned short* bs = Bt + ks * 4096;
    gload16(bs + (size_t)t * 8,         &Bl[t * 8]);
    gload16(bs + (size_t)(t + 256) * 8, &Bl[(t + 256) * 8]);
    __syncthreads();

#pragma unroll
    for (int kk = 0; kk < 2; ++kk) {
      bf16x8 af[4], bfv[2];
#pragma unroll
      for (int mi = 0; mi < 4; ++mi)
        af[mi] = *(const bf16x8*)&Al[((wm * 4 + mi) * 128 + kk * 64 + (lane >> 4) * 16 + (lane & 15)) * 8];
#pragma unroll
      for (int ni = 0; ni < 2; ++ni)
        bfv[ni] = *(const bf16x8*)&Bl[((wn * 2 + ni) * 128 + kk * 64 + (lane >> 4) * 16 + (lane & 15)) * 8];
#pragma unroll
      for (int mi = 0; mi < 4; ++mi)
#pragma unroll
        for (int ni = 0; ni < 2; ++ni)
          acc[mi][ni] = __builtin_amdgcn_mfma_f32_16x16x32_bf16(af[mi], bfv[ni], acc[mi][ni], 0, 0, 0);
    }
    __syncthreads();
  }

#pragma unroll
  for (int mi = 0; mi < 4; ++mi) {
#pragma unroll
    for (int ni = 0; ni < 2; ++ni) {
      int gn = wn * 32 + ni * 16 + (lane & 15);
      float bv = bias[gn];
      int qq = gn >> 4, cc = gn & 15;
#pragma unroll
      for (int j = 0; j < 4; ++j) {
        int gm = m0 + wm * 64 + mi * 16 + (lane >> 4) * 4 + j;
        if (gm < M) {
          float v = acc[mi][ni][j] + bv;
          hq[((size_t)qq * M + gm) * 16 + cc] = f2bf(v);
          y0[((size_t)qq * N1 + gm) * 16 + cc] = f2bf(dis[gm] * v);
        }
      }
    }
  }
}

// ============ quartered PPR step: quarter q pinned to XCDs {2q,2q+1} ============
// y layout [4][N+1][16] bf16 (row N = zeros, pad target). h layout [4][N][16] bf16.
// wave per (row, quarter); lane: g=lane>>3 edge subgroup, lc=lane&7 col pair.
template<bool FINAL>
__global__ __launch_bounds__(256)
void prop_q(const unsigned short* __restrict__ yin, const unsigned short* __restrict__ hq,
            void* __restrict__ yout, const int* __restrict__ rowptr,
            const int* __restrict__ col, const float* __restrict__ dis, int N, int Q) {
  const int x = blockIdx.x;
  const int xcd = x & 7;
  const int q = xcd >> 1;
  const int i = (x >> 3) * 2 + (xcd & 1);
  if (i >= Q) return;
  int r = i * 4 + (threadIdx.x >> 6);
  if (r >= N) return;
  r = __builtin_amdgcn_readfirstlane(r);
  const int lane = threadIdx.x & 63;
  const int g = lane >> 3;
  const int lc = lane & 7;
  const size_t N1 = (size_t)N + 1;
  const unsigned short* yq = yin + (size_t)q * N1 * 16;

  float a0 = 0.f, a1 = 0.f;
  const int start = rowptr[r], end = rowptr[r + 1];
  for (int e = start; e < end; e += 64) {
    int na = end - e; if (na > 64) na = 64;
    int c = N;                                  // pad -> zero row
    if (lane < na) c = col[e + lane];
#pragma unroll 4
    for (int j = 0; j < na; j += 8) {
      int cj = __shfl(c, j + g);
      unsigned v = *(const unsigned*)(yq + (size_t)cj * 16 + 2 * lc);
      a0 += bflo(v); a1 += bfhi(v);
    }
  }
  a0 += __shfl_xor(a0, 8);  a1 += __shfl_xor(a1, 8);
  a0 += __shfl_xor(a0, 16); a1 += __shfl_xor(a1, 16);
  a0 += __shfl_xor(a0, 32); a1 += __shfl_xor(a1, 32);

  float dr = dis[r];
  unsigned sv = *(const unsigned*)(yq + (size_t)r * 16 + 2 * lc);
  unsigned hv = *(const unsigned*)(hq + ((size_t)q * N + r) * 16 + 2 * lc);
  float f0 = ALPHA_F * bflo(hv) + (1.f - ALPHA_F) * dr * (a0 + bflo(sv));
  float f1 = ALPHA_F * bfhi(hv) + (1.f - ALPHA_F) * dr * (a1 + bfhi(sv));
  if (!FINAL) {
    if (g == 0) {
      unsigned o = (unsigned)f2bf(dr * f0) | ((unsigned)f2bf(dr * f1) << 16);
      *(unsigned*)((unsigned short*)yout + ((size_t)q * N1 + r) * 16 + 2 * lc) = o;
    }
  } else {
    if (g == 0) {
      *(float2*)((float*)yout + ((size_t)q * N + r) * 16 + 2 * lc) = make_float2(f0, f1);
    }
  }
}

// fused log_softmax over quartered f32 z -> d_out row-major
__global__ __launch_bounds__(256)
void k_lsm(const float* __restrict__ zfin, float* __restrict__ out, int N) {
  int r = (blockIdx.x * 256 + threadIdx.x) >> 6;
  if (r >= N) return;
  int lane = threadIdx.x & 63;
  float v = zfin[((size_t)(lane >> 4) * N + r) * 16 + (lane & 15)];
  float m = v;
#pragma unroll
  for (int off = 32; off; off >>= 1) m = fmaxf(m, __shfl_xor(m, off));
  float e = __expf(v - m);
  float s = e;
#pragma unroll
  for (int off = 32; off; off >>= 1) s += __shfl_xor(s, off);
  out[(size_t)r * 64 + lane] = v - m - __logf(s);
}

extern "C" void kernel_launch(void* const* d_in, const int* in_sizes, int n_in,
                              void* d_out, int out_size, void* d_ws, size_t ws_size,
                              hipStream_t stream) {
  const float* x  = (const float*)d_in[0];
  const int*   ei = (const int*)d_in[1];
  const float* W1 = (const float*)d_in[2];
  const float* b1 = (const float*)d_in[3];
  const float* W2 = (const float*)d_in[4];
  const float* b2 = (const float*)d_in[5];

  const int IN = 512, HID = 256, OUT = 64;
  const int N = in_sizes[0] / IN;
  const int E = in_sizes[1] / 2;
  const int* srcv = ei;
  const int* dstv = ei + E;
  const int NBUCK = (N + (1 << BKT_SH) - 1) >> BKT_SH;
  const int MT = (N + 127) / 128;
  const size_t N1 = (size_t)N + 1;

  char* p = (char*)d_ws;
  auto alloc = [&](size_t bytes) -> void* {
    void* r = (void*)p;
    p += (bytes + 255) & ~(size_t)255;
    return r;
  };
  int*   bhist  = (int*)alloc(256 * 4);
  int*   bbase  = (int*)alloc(256 * 4);
  int*   gcur   = (int*)alloc(256 * 4);
  int*   counts = (int*)alloc((size_t)N * 4);
  float* dis    = (float*)alloc((size_t)N * 4);
  int*   rowptr = (int*)alloc((size_t)(N + 1) * 4);
  int*   col    = (int*)alloc((size_t)E * 4);
  unsigned short* WT1t = (unsigned short*)alloc((size_t)IN * HID * 2);
  unsigned short* WT2t = (unsigned short*)alloc((size_t)HID * OUT * 2);
  unsigned short* hq   = (unsigned short*)alloc((size_t)N * 64 * 2);      // [4][N][16]
  unsigned short* yA   = (unsigned short*)alloc(N1 * 64 * 2);             // [4][N+1][16]
  // big region R: tmp (build) -> hidT (gemm) -> {zfin | yB} (prop)
  size_t hidT_bytes = (size_t)MT * 32768 * 2;
  size_t zfin_bytes = (size_t)N * 64 * 4;
  size_t yB_bytes   = N1 * 64 * 2;
  size_t R_bytes = hidT_bytes;
  if ((size_t)E * 8 > R_bytes) R_bytes = (size_t)E * 8;
  if (zfin_bytes + 256 + yB_bytes > R_bytes) R_bytes = zfin_bytes + 256 + yB_bytes;
  char* R = (char*)alloc(R_bytes);
  int2* tmp = (int2*)R;
  unsigned short* hidT = (unsigned short*)R;
  float* zfin = (float*)R;
  unsigned short* yB = (unsigned short*)(R + ((zfin_bytes + 255) & ~(size_t)255));

  hipMemsetAsync(bhist, 0, 256 * 4, stream);

  const int p1blocks = (E + P1_CHUNK - 1) / P1_CHUNK;
  p0_hist<<<p1blocks, 256, 0, stream>>>(dstv, E, bhist);
  p0_scan<<<1, 256, 0, stream>>>(bhist, bbase, gcur, rowptr, N, E);
  p1_scatter<<<p1blocks, 256, 0, stream>>>(srcv, dstv, E, gcur, tmp);
  p2_bucket<<<NBUCK, 256, 0, stream>>>(tmp, bbase, bhist, counts, rowptr, col, N);
  k_dis<<<(N + 255) / 256, 256, 0, stream>>>(counts, dis, N);

  k_wconv1<<<(IN * HID + 255) / 256, 256, 0, stream>>>(W1, WT1t);
  k_wconv2<<<(HID * OUT + 255) / 256, 256, 0, stream>>>(W2, WT2t);

  gemm1_kernel<<<MT, 512, 0, stream>>>(x, WT1t, b1, hidT, N);
  gemm2_kernel<<<MT, 256, 0, stream>>>(hidT, WT2t, b2, dis, hq, yA, N);
  k_zrow<<<1, 128, 0, stream>>>(yA, yB, N);

  const int Q = (N + 3) / 4;
  const int pblocks = 8 * ((Q + 1) / 2);
  const unsigned short* ycur = yA;
  for (int it = 0; it < KSTEPS - 1; ++it) {
    unsigned short* ynext = (it & 1) ? yA : yB;
    prop_q<false><<<pblocks, 256, 0, stream>>>(ycur, hq, ynext, rowptr, col, dis, N, Q);
    ycur = ynext;
  }
  prop_q<true><<<pblocks, 256, 0, stream>>>(ycur, hq, zfin, rowptr, col, dis, N, Q);
  k_lsm<<<(N + 3) / 4, 256, 0, stream>>>(zfin, (float*)d_out, N);
}

// Round 7
// 764.783 us; speedup vs baseline: 2.0548x; 2.0548x over previous
//
#include <hip/hip_runtime.h>
#include <hip/hip_bf16.h>

#define ALPHA_F 0.1f
#define KSTEPS 10
#define BKT_SH 9                       // 512 dst rows per bucket
#define P1_CHUNK 8192
#define MAXPAD_PER_BUCKET (512 * 32)   // reserve for row padding to mult-of-32

typedef __attribute__((ext_vector_type(8))) short bf16x8;
typedef __attribute__((ext_vector_type(4))) float f32x4;

__device__ __forceinline__ unsigned short f2bf(float f) {
  union { float f; unsigned int u; } v; v.f = f;
  unsigned int u = v.u;
  u += 0x7FFFu + ((u >> 16) & 1u);   // round-to-nearest-even
  return (unsigned short)(u >> 16);
}
__device__ __forceinline__ float bflo(unsigned int u) { return __uint_as_float(u << 16); }
__device__ __forceinline__ float bfhi(unsigned int u) { return __uint_as_float(u & 0xFFFF0000u); }

__device__ __forceinline__ void gload16(const void* g, void* l) {
  __builtin_amdgcn_global_load_lds(
      (const __attribute__((address_space(1))) void*)g,
      (__attribute__((address_space(3))) void*)l, 16, 0, 0);
}

// ============ CSR build: two-level binned counting sort, padded rows ============

__global__ __launch_bounds__(256)
void p0_hist(const int* __restrict__ dstv, int E, int* __restrict__ bhist) {
  __shared__ int h[256];
  int t = threadIdx.x;
  h[t] = 0;
  __syncthreads();
  int b0 = blockIdx.x * P1_CHUNK;
  int lim = min(P1_CHUNK, E - b0);
  for (int i = t; i < lim; i += 256) atomicAdd(&h[dstv[b0 + i] >> BKT_SH], 1);
  __syncthreads();
  if (h[t]) atomicAdd(&bhist[t], h[t]);
}

__global__ void p0_scan(const int* __restrict__ bhist, int* __restrict__ bbase,
                        int* __restrict__ gcur) {
  __shared__ int s[256];
  int t = threadIdx.x;
  int mine = bhist[t];
  s[t] = mine;
  __syncthreads();
  for (int off = 1; off < 256; off <<= 1) {
    int v = (t >= off) ? s[t - off] : 0;
    __syncthreads();
    s[t] += v;
    __syncthreads();
  }
  int excl = s[t] - mine;
  bbase[t] = excl;
  gcur[t] = excl;
}

__global__ __launch_bounds__(256)
void p1_scatter(const int* __restrict__ srcv, const int* __restrict__ dstv, int E,
                int* __restrict__ gcur, int2* __restrict__ tmp) {
  __shared__ int h[256];
  __shared__ int loc[256];
  int t = threadIdx.x;
  int b0 = blockIdx.x * P1_CHUNK;
  int lim = min(P1_CHUNK, E - b0);
  h[t] = 0;
  __syncthreads();
  for (int i = t; i < lim; i += 256) atomicAdd(&h[dstv[b0 + i] >> BKT_SH], 1);
  __syncthreads();
  loc[t] = h[t] ? atomicAdd(&gcur[t], h[t]) : 0;
  __syncthreads();
  h[t] = 0;
  __syncthreads();
  for (int i = t; i < lim; i += 256) {
    int d = dstv[b0 + i], s = srcv[b0 + i];
    int b = d >> BKT_SH;
    int pos = loc[b] + atomicAdd(&h[b], 1);
    tmp[pos] = make_int2(s, d);
  }
}

// p2: one block per bucket — true counts, PADDED rowptr (mult-of-32 rows),
// in-bucket sort emitting col only; pad slots get col = N (zero row).
__global__ __launch_bounds__(256)
void p2_bucket(const int2* __restrict__ tmp, const int* __restrict__ bbase,
               const int* __restrict__ bhist, int* __restrict__ counts,
               int* __restrict__ rowptr, int* __restrict__ col, int N) {
  __shared__ int h1[512];
  __shared__ int cur[512];
  __shared__ int s2[256];
  const int t = threadIdx.x;
  const int b = blockIdx.x;
  const int base = bbase[b];                    // true base (tmp region)
  const int pbase = base + b * MAXPAD_PER_BUCKET;  // padded base (col region)
  const int sz = bhist[b];
  const int r0 = b << BKT_SH;
  const int nrows = min(512, N - r0);

  h1[t] = 0; h1[t + 256] = 0;
  __syncthreads();
  for (int i = t; i < sz; i += 256) atomicAdd(&h1[tmp[base + i].y - r0], 1);
  __syncthreads();
  // exclusive scan of PADDED sizes
  int a = (h1[2 * t] + 31) & ~31;
  int c = (h1[2 * t + 1] + 31) & ~31;
  s2[t] = a + c;
  __syncthreads();
  for (int off = 1; off < 256; off <<= 1) {
    int v = (t >= off) ? s2[t - off] : 0;
    __syncthreads();
    s2[t] += v;
    __syncthreads();
  }
  int excl2 = s2[t] - (a + c);
  cur[2 * t] = excl2;
  cur[2 * t + 1] = excl2 + a;
  __syncthreads();
  if (t < nrows)       { rowptr[r0 + t] = pbase + cur[t];             counts[r0 + t] = h1[t]; }
  if (t + 256 < nrows) { rowptr[r0 + t + 256] = pbase + cur[t + 256]; counts[r0 + t + 256] = h1[t + 256]; }
  __syncthreads();
  // scatter real edges
  for (int i = t; i < sz; i += 256) {
    int2 e = tmp[base + i];
    int p = pbase + atomicAdd(&cur[e.y - r0], 1);
    col[p] = e.x;
  }
  __syncthreads();
  // fill pads: after scatter, cur[i] == padded_start + cnt
  for (int i = t; i < nrows; i += 256) {
    int cnt = h1[i];
    int c32 = (cnt + 31) & ~31;
    int ps = pbase + cur[i];
    for (int k = cnt; k < c32; ++k) col[ps++] = N;
  }
}

__global__ void k_dis(const int* __restrict__ counts, float* __restrict__ dis, int N) {
  int i = blockIdx.x * 256 + threadIdx.x;
  if (i < N) dis[i] = rsqrtf((float)(counts[i] + 1));  // +1 self-loop
}

// zero pad row N of both y buffers (row-major [N+1][64] bf16)
__global__ void k_zrow(unsigned short* __restrict__ yA, unsigned short* __restrict__ yB, int N) {
  int t = threadIdx.x;                 // 128 threads
  if (t < 64) yA[(size_t)N * 64 + t] = 0;
  else        yB[(size_t)N * 64 + (t - 64)] = 0;
}

// ============ weight conversion to MFMA-native tiled layouts ============
// W1 [512][256] -> WT1t: [kstep8][nsub16][q8][n16][e8]
__global__ void k_wconv1(const float* __restrict__ W, unsigned short* __restrict__ WT) {
  int idx = blockIdx.x * 256 + threadIdx.x;
  if (idx >= 512 * 256) return;
  int e = idx & 7, n = (idx >> 3) & 15, q = (idx >> 7) & 7;
  int nsub = (idx >> 10) & 15, kstep = idx >> 14;
  int k = kstep * 64 + q * 8 + e;
  int ncol = nsub * 16 + n;
  WT[idx] = f2bf(W[(size_t)k * 256 + ncol]);
}

// W2 [256][64] -> WT2t: [kstep4][nsub4][q8][n16][e8]
__global__ void k_wconv2(const float* __restrict__ W, unsigned short* __restrict__ WT) {
  int idx = blockIdx.x * 256 + threadIdx.x;
  if (idx >= 256 * 64) return;
  int e = idx & 7, n = (idx >> 3) & 15, q = (idx >> 7) & 7;
  int nsub = (idx >> 10) & 3, kstep = idx >> 12;
  int k = kstep * 64 + q * 8 + e;
  int ncol = nsub * 16 + n;
  WT[idx] = f2bf(W[(size_t)k * 64 + ncol]);
}

// ============ GEMM1: hid_tiled = relu(x @ W1 + b1), BM=128 BN=256 BK=64 ============
__global__ __launch_bounds__(512)
void gemm1_kernel(const float* __restrict__ X, const unsigned short* __restrict__ Bt,
                  const float* __restrict__ bias, unsigned short* __restrict__ outT,
                  int M) {
  __shared__ __align__(16) unsigned short Al[8192];    // 16 KB
  __shared__ __align__(16) unsigned short Bl[16384];   // 32 KB
  const int t = threadIdx.x;
  const int m0 = blockIdx.x * 128;
  const int lane = t & 63;
  const int w = t >> 6;
  const int wm = w >> 2, wn = w & 3;

  const int sm = ((t >> 7) << 4) + (t & 15);
  const int sq = (t >> 4) & 7;
  const int r1 = m0 + sm;
  const int r2 = r1 + 64;
  const bool g1 = r1 < M, g2 = r2 < M;

  f32x4 acc[4][4] = {};

  for (int ks = 0; ks < 8; ++ks) {
    const int kc = ks * 64 + sq * 8;
    uint4 v1 = {0, 0, 0, 0}, v2 = {0, 0, 0, 0};
    if (g1) {
      const float* p = X + (size_t)r1 * 512 + kc;
      float4 a = *(const float4*)p, b = *(const float4*)(p + 4);
      unsigned short* o = (unsigned short*)&v1;
      o[0] = f2bf(a.x); o[1] = f2bf(a.y); o[2] = f2bf(a.z); o[3] = f2bf(a.w);
      o[4] = f2bf(b.x); o[5] = f2bf(b.y); o[6] = f2bf(b.z); o[7] = f2bf(b.w);
    }
    if (g2) {
      const float* p = X + (size_t)r2 * 512 + kc;
      float4 a = *(const float4*)p, b = *(const float4*)(p + 4);
      unsigned short* o = (unsigned short*)&v2;
      o[0] = f2bf(a.x); o[1] = f2bf(a.y); o[2] = f2bf(a.z); o[3] = f2bf(a.w);
      o[4] = f2bf(b.x); o[5] = f2bf(b.y); o[6] = f2bf(b.z); o[7] = f2bf(b.w);
    }
    *(uint4*)&Al[t * 8] = v1;
    *(uint4*)&Al[(t + 512) * 8] = v2;

    const unsigned short* bs = Bt + ks * 16384;
    gload16(bs + (size_t)t * 8,          &Bl[t * 8]);
    gload16(bs + (size_t)(t + 512) * 8,  &Bl[(t + 512) * 8]);
    gload16(bs + (size_t)(t + 1024) * 8, &Bl[(t + 1024) * 8]);
    gload16(bs + (size_t)(t + 1536) * 8, &Bl[(t + 1536) * 8]);
    __syncthreads();

#pragma unroll
    for (int kk = 0; kk < 2; ++kk) {
      bf16x8 af[4], bfv[4];
#pragma unroll
      for (int mi = 0; mi < 4; ++mi)
        af[mi] = *(const bf16x8*)&Al[((wm * 4 + mi) * 128 + kk * 64 + (lane >> 4) * 16 + (lane & 15)) * 8];
#pragma unroll
      for (int ni = 0; ni < 4; ++ni)
        bfv[ni] = *(const bf16x8*)&Bl[((wn * 4 + ni) * 128 + kk * 64 + (lane >> 4) * 16 + (lane & 15)) * 8];
#pragma unroll
      for (int mi = 0; mi < 4; ++mi)
#pragma unroll
        for (int ni = 0; ni < 4; ++ni)
          acc[mi][ni] = __builtin_amdgcn_mfma_f32_16x16x32_bf16(af[mi], bfv[ni], acc[mi][ni], 0, 0, 0);
    }
    __syncthreads();
  }

  unsigned short* ob = outT + (size_t)blockIdx.x * 32768;
#pragma unroll
  for (int mi = 0; mi < 4; ++mi) {
#pragma unroll
    for (int ni = 0; ni < 4; ++ni) {
      int n = wn * 64 + ni * 16 + (lane & 15);
      float bv = bias[n];
      int kstep = n >> 6, q = (n >> 3) & 7, e = n & 7;
#pragma unroll
      for (int j = 0; j < 4; ++j) {
        int lm = wm * 64 + mi * 16 + (lane >> 4) * 4 + j;
        if (m0 + lm < M) {
          float v = fmaxf(acc[mi][ni][j] + bv, 0.f);
          int msub = lm >> 4, mm = lm & 15;
          ob[((((kstep * 8 + msub) * 8 + q) * 16 + mm) * 8) + e] = f2bf(v);
        }
      }
    }
  }
}

// ============ GEMM2: hb = hid @ W2 + b2 (row-major bf16) and y0 = bf16(dis*h) ============
__global__ __launch_bounds__(256)
void gemm2_kernel(const unsigned short* __restrict__ At, const unsigned short* __restrict__ Bt,
                  const float* __restrict__ bias, const float* __restrict__ dis,
                  unsigned short* __restrict__ hb, unsigned short* __restrict__ y0, int M) {
  __shared__ __align__(16) unsigned short Al[8192];
  __shared__ __align__(16) unsigned short Bl[4096];
  const int t = threadIdx.x;
  const int m0 = blockIdx.x * 128;
  const int lane = t & 63;
  const int w = t >> 6;
  const int wm = w >> 1, wn = w & 1;

  f32x4 acc[4][2] = {};

  const unsigned short* ab = At + (size_t)blockIdx.x * 32768;
  for (int ks = 0; ks < 4; ++ks) {
    const unsigned short* as = ab + ks * 8192;
    gload16(as + (size_t)t * 8,         &Al[t * 8]);
    gload16(as + (size_t)(t + 256) * 8, &Al[(t + 256) * 8]);
    gload16(as + (size_t)(t + 512) * 8, &Al[(t + 512) * 8]);
    gload16(as + (size_t)(t + 768) * 8, &Al[(t + 768) * 8]);
    const unsigned short* bs = Bt + ks * 4096;
    gload16(bs + (size_t)t * 8,         &Bl[t * 8]);
    gload16(bs + (size_t)(t + 256) * 8, &Bl[(t + 256) * 8]);
    __syncthreads();

#pragma unroll
    for (int kk = 0; kk < 2; ++kk) {
      bf16x8 af[4], bfv[2];
#pragma unroll
      for (int mi = 0; mi < 4; ++mi)
        af[mi] = *(const bf16x8*)&Al[((wm * 4 + mi) * 128 + kk * 64 + (lane >> 4) * 16 + (lane & 15)) * 8];
#pragma unroll
      for (int ni = 0; ni < 2; ++ni)
        bfv[ni] = *(const bf16x8*)&Bl[((wn * 2 + ni) * 128 + kk * 64 + (lane >> 4) * 16 + (lane & 15)) * 8];
#pragma unroll
      for (int mi = 0; mi < 4; ++mi)
#pragma unroll
        for (int ni = 0; ni < 2; ++ni)
          acc[mi][ni] = __builtin_amdgcn_mfma_f32_16x16x32_bf16(af[mi], bfv[ni], acc[mi][ni], 0, 0, 0);
    }
    __syncthreads();
  }

#pragma unroll
  for (int mi = 0; mi < 4; ++mi) {
#pragma unroll
    for (int ni = 0; ni < 2; ++ni) {
      int gn = wn * 32 + ni * 16 + (lane & 15);
      float bv = bias[gn];
#pragma unroll
      for (int j = 0; j < 4; ++j) {
        int gm = m0 + wm * 64 + mi * 16 + (lane >> 4) * 4 + j;
        if (gm < M) {
          float v = acc[mi][ni][j] + bv;
          hb[(size_t)gm * 64 + gn] = f2bf(v);
          y0[(size_t)gm * 64 + gn] = f2bf(dis[gm] * v);
        }
      }
    }
  }
}

// ============ PPR diffusion: one wave per dst row, y-trick, padded edges ============
// y = dis .* z, bf16 [N+1][64] (row N zeros). Per iter: 32 edges, group g (8 lanes)
// handles edges 4g..4g+3 via one int4 col load + 4 independent dwordx4 gathers.
template<bool FINAL>
__global__ __launch_bounds__(256)
void prop_kernel(const unsigned short* __restrict__ yin,
                 const unsigned short* __restrict__ hb,
                 void* __restrict__ yout,
                 const int* __restrict__ rowptr, const int* __restrict__ counts,
                 const int* __restrict__ col, const float* __restrict__ dis, int N) {
  int wid = (blockIdx.x * 256 + threadIdx.x) >> 6;
  wid = __builtin_amdgcn_readfirstlane(wid);   // wave-uniform -> scalar loads
  if (wid >= N) return;
  const int lane = threadIdx.x & 63;
  const int g = lane >> 3;
  const int lg = lane & 7;
  const int r = wid;

  const int start = rowptr[r];
  const int cnt = counts[r];
  const int iters = (cnt + 31) >> 5;
  const float dr = dis[r];
  // independent loads issued early
  uint4 zs = *(const uint4*)(yin + (size_t)r * 64 + 8 * lg);
  uint4 hr = *(const uint4*)(hb + (size_t)r * 64 + 8 * lg);

  float acc[8] = {0.f, 0.f, 0.f, 0.f, 0.f, 0.f, 0.f, 0.f};
  const int* cp = col + start + 4 * g;
  for (int it = 0; it < iters; ++it, cp += 32) {
    int4 cc = *(const int4*)cp;
    uint4 z0 = *(const uint4*)(yin + (size_t)cc.x * 64 + 8 * lg);
    uint4 z1 = *(const uint4*)(yin + (size_t)cc.y * 64 + 8 * lg);
    uint4 z2 = *(const uint4*)(yin + (size_t)cc.z * 64 + 8 * lg);
    uint4 z3 = *(const uint4*)(yin + (size_t)cc.w * 64 + 8 * lg);
    acc[0] += bflo(z0.x); acc[1] += bfhi(z0.x); acc[2] += bflo(z0.y); acc[3] += bfhi(z0.y);
    acc[4] += bflo(z0.z); acc[5] += bfhi(z0.z); acc[6] += bflo(z0.w); acc[7] += bfhi(z0.w);
    acc[0] += bflo(z1.x); acc[1] += bfhi(z1.x); acc[2] += bflo(z1.y); acc[3] += bfhi(z1.y);
    acc[4] += bflo(z1.z); acc[5] += bfhi(z1.z); acc[6] += bflo(z1.w); acc[7] += bfhi(z1.w);
    acc[0] += bflo(z2.x); acc[1] += bfhi(z2.x); acc[2] += bflo(z2.y); acc[3] += bfhi(z2.y);
    acc[4] += bflo(z2.z); acc[5] += bfhi(z2.z); acc[6] += bflo(z2.w); acc[7] += bfhi(z2.w);
    acc[0] += bflo(z3.x); acc[1] += bfhi(z3.x); acc[2] += bflo(z3.y); acc[3] += bfhi(z3.y);
    acc[4] += bflo(z3.z); acc[5] += bfhi(z3.z); acc[6] += bflo(z3.w); acc[7] += bfhi(z3.w);
  }
  // reduce across the 8 edge-groups (lane bits 3..5)
#pragma unroll
  for (int k = 0; k < 8; ++k) {
    acc[k] += __shfl_xor(acc[k], 8);
    acc[k] += __shfl_xor(acc[k], 16);
    acc[k] += __shfl_xor(acc[k], 32);
  }

  float selfz[8] = { bflo(zs.x), bfhi(zs.x), bflo(zs.y), bfhi(zs.y),
                     bflo(zs.z), bfhi(zs.z), bflo(zs.w), bfhi(zs.w) };
  float hv[8]    = { bflo(hr.x), bfhi(hr.x), bflo(hr.y), bfhi(hr.y),
                     bflo(hr.z), bfhi(hr.z), bflo(hr.w), bfhi(hr.w) };
  float f[8];
#pragma unroll
  for (int k = 0; k < 8; ++k)
    f[k] = ALPHA_F * hv[k] + (1.f - ALPHA_F) * dr * (acc[k] + selfz[k]);

  if (!FINAL) {
    if (g == 0) {
      uint4 o;
      o.x = (unsigned)f2bf(dr * f[0]) | ((unsigned)f2bf(dr * f[1]) << 16);
      o.y = (unsigned)f2bf(dr * f[2]) | ((unsigned)f2bf(dr * f[3]) << 16);
      o.z = (unsigned)f2bf(dr * f[4]) | ((unsigned)f2bf(dr * f[5]) << 16);
      o.w = (unsigned)f2bf(dr * f[6]) | ((unsigned)f2bf(dr * f[7]) << 16);
      *(uint4*)((unsigned short*)yout + (size_t)r * 64 + 8 * lg) = o;
    }
  } else {
    float m = f[0];
#pragma unroll
    for (int k = 1; k < 8; ++k) m = fmaxf(m, f[k]);
    m = fmaxf(m, __shfl_xor(m, 1));
    m = fmaxf(m, __shfl_xor(m, 2));
    m = fmaxf(m, __shfl_xor(m, 4));
    float s = 0.f;
#pragma unroll
    for (int k = 0; k < 8; ++k) s += __expf(f[k] - m);
    s += __shfl_xor(s, 1);
    s += __shfl_xor(s, 2);
    s += __shfl_xor(s, 4);
    float ls = __logf(s);
    if (g == 0) {
      float* op = (float*)yout + (size_t)r * 64 + 8 * lg;
      *(float4*)op       = make_float4(f[0] - m - ls, f[1] - m - ls, f[2] - m - ls, f[3] - m - ls);
      *(float4*)(op + 4) = make_float4(f[4] - m - ls, f[5] - m - ls, f[6] - m - ls, f[7] - m - ls);
    }
  }
}

extern "C" void kernel_launch(void* const* d_in, const int* in_sizes, int n_in,
                              void* d_out, int out_size, void* d_ws, size_t ws_size,
                              hipStream_t stream) {
  const float* x  = (const float*)d_in[0];
  const int*   ei = (const int*)d_in[1];
  const float* W1 = (const float*)d_in[2];
  const float* b1 = (const float*)d_in[3];
  const float* W2 = (const float*)d_in[4];
  const float* b2 = (const float*)d_in[5];

  const int IN = 512, HID = 256, OUT = 64;
  const int N = in_sizes[0] / IN;
  const int E = in_sizes[1] / 2;
  const int* srcv = ei;
  const int* dstv = ei + E;
  const int NBUCK = (N + (1 << BKT_SH) - 1) >> BKT_SH;
  const int MT = (N + 127) / 128;
  const size_t N1 = (size_t)N + 1;

  char* p = (char*)d_ws;
  auto alloc = [&](size_t bytes) -> void* {
    void* r = (void*)p;
    p += (bytes + 255) & ~(size_t)255;
    return r;
  };
  int*   bhist  = (int*)alloc(256 * 4);
  int*   bbase  = (int*)alloc(256 * 4);
  int*   gcur   = (int*)alloc(256 * 4);
  int*   counts = (int*)alloc((size_t)N * 4);
  float* dis    = (float*)alloc((size_t)N * 4);
  int*   rowptr = (int*)alloc((size_t)(N + 1) * 4);
  int*   col    = (int*)alloc(((size_t)E + 256 * MAXPAD_PER_BUCKET) * 4);
  unsigned short* WT1t = (unsigned short*)alloc((size_t)IN * HID * 2);
  unsigned short* WT2t = (unsigned short*)alloc((size_t)HID * OUT * 2);
  unsigned short* hb   = (unsigned short*)alloc((size_t)N * OUT * 2);    // bf16 h [N][64]
  unsigned short* yA   = (unsigned short*)alloc(N1 * OUT * 2);           // y [N+1][64]
  // region R: tmp (build) -> hidT (gemm) -> yB (prop)
  size_t hidT_bytes = (size_t)MT * 32768 * 2;
  size_t R_bytes = hidT_bytes;
  if ((size_t)E * 8 > R_bytes) R_bytes = (size_t)E * 8;
  if (N1 * OUT * 2 > R_bytes) R_bytes = N1 * OUT * 2;
  char* R = (char*)alloc(R_bytes);
  int2* tmp = (int2*)R;
  unsigned short* hidT = (unsigned short*)R;
  unsigned short* yB = (unsigned short*)R;

  hipMemsetAsync(bhist, 0, 256 * 4, stream);

  const int p1blocks = (E + P1_CHUNK - 1) / P1_CHUNK;
  p0_hist<<<p1blocks, 256, 0, stream>>>(dstv, E, bhist);
  p0_scan<<<1, 256, 0, stream>>>(bhist, bbase, gcur);
  p1_scatter<<<p1blocks, 256, 0, stream>>>(srcv, dstv, E, gcur, tmp);
  p2_bucket<<<NBUCK, 256, 0, stream>>>(tmp, bbase, bhist, counts, rowptr, col, N);
  k_dis<<<(N + 255) / 256, 256, 0, stream>>>(counts, dis, N);

  k_wconv1<<<(IN * HID + 255) / 256, 256, 0, stream>>>(W1, WT1t);
  k_wconv2<<<(HID * OUT + 255) / 256, 256, 0, stream>>>(W2, WT2t);

  gemm1_kernel<<<MT, 512, 0, stream>>>(x, WT1t, b1, hidT, N);
  gemm2_kernel<<<MT, 256, 0, stream>>>(hidT, WT2t, b2, dis, hb, yA, N);
  k_zrow<<<1, 128, 0, stream>>>(yA, yB, N);

  const int pblocks = (N + 3) / 4;
  const unsigned short* ycur = yA;
  for (int it = 0; it < KSTEPS - 1; ++it) {
    unsigned short* ynext = (it & 1) ? yA : yB;
    prop_kernel<false><<<pblocks, 256, 0, stream>>>(ycur, hb, ynext, rowptr, counts, col, dis, N);
    ycur = ynext;
  }
  prop_kernel<true><<<pblocks, 256, 0, stream>>>(ycur, hb, d_out, rowptr, counts, col, dis, N);
}